// Round 10
// baseline (607.315 us; speedup 1.0000x reference)
//
#include <hip/hip_runtime.h>

typedef _Float16 f16;
typedef _Float16 h8   __attribute__((ext_vector_type(8)));
typedef float    fx16 __attribute__((ext_vector_type(16)));
typedef float    fl2  __attribute__((ext_vector_type(2)));
typedef unsigned int u32x4 __attribute__((ext_vector_type(4)));

#define BATCH   262144
#define SEQ_LEN 30
#define DT      0.03f
#define N2LOG2E (-2.8853900817779268f)

__device__ __forceinline__ float rcpf(float x) { return __builtin_amdgcn_rcpf(x); }
__device__ __forceinline__ float ex2(float x)  { return __builtin_amdgcn_exp2f(x); }
__device__ __forceinline__ float hsum8(h8 v) {
    _Float16 a0 = (_Float16)(v[0] + v[4]);
    _Float16 a1 = (_Float16)(v[1] + v[5]);
    _Float16 a2 = (_Float16)(v[2] + v[6]);
    _Float16 a3 = (_Float16)(v[3] + v[7]);
    return ((float)(_Float16)(a0 + a2)) + ((float)(_Float16)(a1 + a3));
}

// wsh image (f16 units):
//  [0, 20480)     WMAIN frag ((G*4+g)*5+kk) x 64 lanes x 8:
//                 n = g*64 + G*32 + (l&31), k = kk*16 + (l>>5)*8 + e
//                 k<64: W_hh[n][k]*sc; 64-67: Weff[n][k-64]*sc; 68: beff[n]*sc; else 0
//                 sc = -log2(e) for gates i,f,o; -2*log2(e) for gate g
//  [20480, 27648) WINIT frag (G*7+kk2) x 64 x 8 (unscaled)
//  [27648, 27776) WCTRL
__global__ void prep_kernel(const float* __restrict__ W_emb,
                            const float* __restrict__ b_emb,
                            const float* __restrict__ W_ih,
                            const float* __restrict__ b_ih,
                            const float* __restrict__ b_hh,
                            const float* __restrict__ W_hh,
                            const float* __restrict__ W_ctrl,
                            const float* __restrict__ W_init,
                            const float* __restrict__ b_init,
                            f16* __restrict__ wsh) {
    __shared__ float weff_s[256][4];
    __shared__ float beff_s[256];
    {
        int r = threadIdx.x;
        float a0 = 0.f, a1 = 0.f, a2 = 0.f, a3 = 0.f;
        float bb = b_ih[r] + b_hh[r];
        for (int k = 0; k < 64; ++k) {
            float w = W_ih[r * 64 + k];
            a0 = fmaf(w, W_emb[k * 4 + 0], a0);
            a1 = fmaf(w, W_emb[k * 4 + 1], a1);
            a2 = fmaf(w, W_emb[k * 4 + 2], a2);
            a3 = fmaf(w, W_emb[k * 4 + 3], a3);
            bb = fmaf(w, b_emb[k], bb);
        }
        weff_s[r][0] = a0; weff_s[r][1] = a1;
        weff_s[r][2] = a2; weff_s[r][3] = a3;
        beff_s[r] = bb;
    }
    __syncthreads();
    for (int idx = threadIdx.x; idx < 20480; idx += 256) {
        int frag = idx >> 9, rem = idx & 511;
        int l = rem >> 3, e = rem & 7;
        int G  = frag / 20;
        int g  = (frag / 5) & 3;
        int kk = frag % 5;
        int n = g * 64 + G * 32 + (l & 31);
        int k = kk * 16 + (l >> 5) * 8 + e;
        float sc = (g == 2) ? -2.8853900817779268f : -1.4426950408889634f;
        float v;
        if      (k < 64)  v = W_hh[n * 64 + k];
        else if (k < 68)  v = weff_s[n][k - 64];
        else if (k == 68) v = beff_s[n];
        else              v = 0.0f;
        wsh[idx] = (f16)(v * sc);
    }
    for (int idx = threadIdx.x; idx < 7168; idx += 256) {
        int fr = idx >> 9, rem = idx & 511;
        int l = rem >> 3, e = rem & 7;
        int G = fr / 7, kk2 = fr % 7;
        int n = G * 32 + (l & 31);
        int k = kk2 * 16 + (l >> 5) * 8 + e;
        float v = (k < 100) ? W_init[n * 100 + k]
                            : ((k == 100) ? b_init[n] : 0.0f);
        wsh[20480 + idx] = (f16)v;
    }
    if (threadIdx.x < 128) wsh[27648 + threadIdx.x] = (f16)W_ctrl[threadIdx.x];
}

__launch_bounds__(512, 4)
__global__ void rollout_kernel(const float* __restrict__ z,
                               const float* __restrict__ init_state,
                               const float* __restrict__ b_ctrl,
                               const f16* __restrict__ wsh,
                               float* __restrict__ out) {
    __shared__ __align__(16) f16 wmain[20480];       // 40 KB
    __shared__ __align__(16) f16 htile[2][4][2048];  // ping-pong, 32 KB
    __shared__ __align__(16) f16 wctrl[128];

    const int tid  = threadIdx.x;
    const int lane = tid & 63;
    const int wv   = tid >> 6;
    const int team = wv >> 1;
    const int G    = wv & 1;
    const int lrow = lane & 31;
    const int hi   = lane >> 5;
    const int rowbase = blockIdx.x * 128 + team * 32;
    const int lane16  = lane * 16;

    {   // stage weights
        const uint4* src = (const uint4*)wsh;
        uint4* dst = (uint4*)wmain;
        for (int i = tid; i < 2560; i += 512) dst[i] = src[i];
        if (tid < 16) ((uint4*)wctrl)[tid] = ((const uint4*)(wsh + 27648))[tid];
    }

    char* hb       = (char*)&htile[0][team][0];   // +16384 -> buffer 1
    const char* wm = (const char*)wmain;
    const char* wc = (const char*)wctrl;

    // precomputed swizzled LDS byte offsets (loop-invariant)
    const unsigned swz  = (unsigned)((lrow & 7) << 4);
    const unsigned col2 = (unsigned)((G * 32 + lrow) * 2);
    u32x4 rav, rcv, wbv;
    #pragma unroll
    for (int q = 0; q < 4; ++q) {
        rav[q] = (unsigned)(lrow * 128) + ((unsigned)(q * 32 + hi * 16) ^ swz);
        rcv[q] = (unsigned)(lrow * 128) + ((unsigned)(hi * 64 + q * 16) ^ swz);
        wbv[q] = (unsigned)(hi * 512) + (col2 ^ (unsigned)((q + 4 * hi) << 4));
    }

    // ---- init: c0 = h0 = z @ W_init^T + b_init (K=112, bias at k=100) ----
    fx16 cv = {};
    {
        const float* zr   = z + (size_t)(rowbase + lrow) * 100;
        const f16*   wini = wsh + 20480 + G * 7 * 512;
        #pragma unroll
        for (int kk = 0; kk < 6; ++kk) {
            const float4 z0 = *(const float4*)(zr + kk * 16 + hi * 8);
            const float4 z1 = *(const float4*)(zr + kk * 16 + hi * 8 + 4);
            h8 av;
            av[0] = (f16)z0.x; av[1] = (f16)z0.y; av[2] = (f16)z0.z; av[3] = (f16)z0.w;
            av[4] = (f16)z1.x; av[5] = (f16)z1.y; av[6] = (f16)z1.z; av[7] = (f16)z1.w;
            h8 bv = *(const h8*)(wini + kk * 512 + lane * 8);
            cv = __builtin_amdgcn_mfma_f32_32x32x16_f16(av, bv, cv, 0, 0, 0);
        }
        {
            h8 av = {};
            if (hi == 0) {
                const float4 z0 = *(const float4*)(zr + 96);
                av[0] = (f16)z0.x; av[1] = (f16)z0.y;
                av[2] = (f16)z0.z; av[3] = (f16)z0.w;
                av[4] = (f16)1.0f;       // k=100 -> bias
            }
            h8 bv = *(const h8*)(wini + 6 * 512 + lane * 8);
            cv = __builtin_amdgcn_mfma_f32_32x32x16_f16(av, bv, cv, 0, 0, 0);
        }
        #pragma unroll
        for (int r = 0; r < 16; ++r)
            *(f16*)(hb + wbv[r & 3] + ((r >> 2) * 1024 + (r & 3) * 128))
                = (f16)cv[r];
    }

    // plant state: every lane holds row (rowbase + lrow)
    float4 s0 = ((const float4*)init_state)[rowbase + lrow];
    float sx = s0.x, sy = s0.y, sz = s0.z, sw = s0.w;
    const float bc0 = b_ctrl[0], bc1 = b_ctrl[1];
    float4* op = (float4*)out + (size_t)(rowbase + lrow) * SEQ_LEN;

    __syncthreads();   // weights + h0 visible

#define MM(KK, AF)                                                             \
    { h8 bI = *(const h8*)(wm + ((G * 4 + 0) * 5 + (KK)) * 1024 + lane16);     \
      h8 bF = *(const h8*)(wm + ((G * 4 + 1) * 5 + (KK)) * 1024 + lane16);     \
      h8 bG = *(const h8*)(wm + ((G * 4 + 2) * 5 + (KK)) * 1024 + lane16);     \
      h8 bO = *(const h8*)(wm + ((G * 4 + 3) * 5 + (KK)) * 1024 + lane16);     \
      aI  = __builtin_amdgcn_mfma_f32_32x32x16_f16(AF, bI, aI,  0, 0, 0);      \
      aF  = __builtin_amdgcn_mfma_f32_32x32x16_f16(AF, bF, aF,  0, 0, 0);      \
      aGt = __builtin_amdgcn_mfma_f32_32x32x16_f16(AF, bG, aGt, 0, 0, 0);      \
      aO  = __builtin_amdgcn_mfma_f32_32x32x16_f16(AF, bO, aO,  0, 0, 0); }

// POFS/QOFS are literal 0/16384 (ping-pong buffer byte offsets)
#define STEP(POFS, QOFS, T) do {                                               \
    h8 af0 = *(const h8*)(hb + (POFS) + rav[0]);                               \
    h8 af1 = *(const h8*)(hb + (POFS) + rav[1]);                               \
    h8 af2 = *(const h8*)(hb + (POFS) + rav[2]);                               \
    h8 af3 = *(const h8*)(hb + (POFS) + rav[3]);                               \
    h8 af4 = {};                                                               \
    if (hi == 0) {                                                             \
        af4[0] = (f16)sx; af4[1] = (f16)sy;                                    \
        af4[2] = (f16)sz; af4[3] = (f16)sw;                                    \
        af4[4] = (f16)1.0f;                                                    \
    }                                                                          \
    fx16 aI = {}, aF = {}, aGt = {}, aO = {};                                  \
    __builtin_amdgcn_s_setprio(1);                                             \
    MM(0, af0) MM(1, af1) MM(2, af2) MM(3, af3) MM(4, af4)                     \
    __builtin_amdgcn_s_setprio(0);                                             \
    _Pragma("unroll")                                                          \
    for (int r2 = 0; r2 < 8; ++r2) {                                           \
        const int r = 2 * r2;                                                  \
        fl2 eI = { ex2(aI[r]),  ex2(aI[r + 1])  };                             \
        fl2 eF = { ex2(aF[r]),  ex2(aF[r + 1])  };                             \
        fl2 eG = { ex2(aGt[r]), ex2(aGt[r + 1]) };                             \
        fl2 eO = { ex2(aO[r]),  ex2(aO[r + 1])  };                             \
        fl2 pF  = 1.0f + eF;                                                   \
        fl2 P   = (1.0f + eI) * (1.0f + eG);                                   \
        fl2 cvp = { cv[r], cv[r + 1] };                                        \
        fl2 num = __builtin_elementwise_fma(cvp, P, (1.0f - eG) * pF);         \
        fl2 dP  = pF * P;                                                      \
        fl2 rdP = { rcpf(dP[0]), rcpf(dP[1]) };                                \
        fl2 cc  = num * rdP;                                                   \
        cv[r] = cc[0]; cv[r + 1] = cc[1];                                      \
        fl2 ccn = cc * N2LOG2E;                                                \
        fl2 eC  = { ex2(ccn[0]), ex2(ccn[1]) };                                \
        fl2 den = (1.0f + eO) * (1.0f + eC);                                   \
        fl2 rdn = { rcpf(den[0]), rcpf(den[1]) };                              \
        fl2 hn  = (1.0f - eC) * rdn;                                           \
        *(f16*)(hb + (QOFS) + wbv[r & 3] + ((r >> 2) * 1024 + (r & 3) * 128))  \
            = (f16)hn[0];                                                      \
        *(f16*)(hb + (QOFS) + wbv[(r + 1) & 3]                                 \
                + (((r + 1) >> 2) * 1024 + ((r + 1) & 3) * 128))               \
            = (f16)hn[1];                                                      \
    }                                                                          \
    __syncthreads();                                                           \
    h8 pv = {}, qv = {};                                                       \
    _Pragma("unroll")                                                          \
    for (int jj = 0; jj < 4; ++jj) {                                           \
        h8 hv = *(const h8*)(hb + (QOFS) + rcv[jj]);                           \
        h8 w0 = *(const h8*)(wc + hi * 64 + jj * 16);                          \
        h8 w1 = *(const h8*)(wc + 128 + hi * 64 + jj * 16);                    \
        pv = __builtin_elementwise_fma(hv, w0, pv);                            \
        qv = __builtin_elementwise_fma(hv, w1, qv);                            \
    }                                                                          \
    float pp = hsum8(pv), qq = hsum8(qv);                                      \
    float ped = bc0 + pp + __shfl_xor(pp, 32);                                 \
    float str = bc1 + qq + __shfl_xor(qq, 32);                                 \
    float beta = fminf(0.5f, fmaxf(-0.5f, str));                               \
    float v1   = fminf(10.0f, fmaxf(0.0f, fmaf(ped, DT, sw)));                 \
    float cpsi = __cosf(sz);                                                   \
    float spsi = __sinf(sz);                                                   \
    float b2   = beta * beta;                                                  \
    float tb   = beta * fmaf(b2, fmaf(b2, fmaf(b2, 0.05396825397f,             \
                         0.13333333333f), 0.33333333333f), 1.0f);              \
    float psid = fminf(1.57f, fmaxf(-1.57f, sw * tb * 0.4f));                  \
    sx = fmaf(v1 * cpsi, DT, sx);                                              \
    sy = fmaf(v1 * spsi, DT, sy);                                              \
    sz = fmaf(psid, DT, sz);                                                   \
    sw = v1;                                                                   \
    if (G == 0 && lane < 32) op[(T)] = make_float4(sx, sy, sz, sw);            \
} while (0)

    #pragma unroll 1
    for (int t2 = 0; t2 < SEQ_LEN; t2 += 2) {
        STEP(0, 16384, t2);
        STEP(16384, 0, t2 + 1);
    }
#undef STEP
#undef MM
}

extern "C" void kernel_launch(void* const* d_in, const int* in_sizes, int n_in,
                              void* d_out, int out_size, void* d_ws, size_t ws_size,
                              hipStream_t stream) {
    const float* z          = (const float*)d_in[0];
    const float* init_state = (const float*)d_in[1];
    const float* W_emb      = (const float*)d_in[2];
    const float* b_emb      = (const float*)d_in[3];
    const float* W_ih       = (const float*)d_in[4];
    const float* W_hh       = (const float*)d_in[5];
    const float* b_ih       = (const float*)d_in[6];
    const float* b_hh       = (const float*)d_in[7];
    const float* W_ctrl     = (const float*)d_in[8];
    const float* b_ctrl     = (const float*)d_in[9];
    const float* W_init     = (const float*)d_in[10];
    const float* b_init     = (const float*)d_in[11];
    float* out = (float*)d_out;
    f16*   wsh = (f16*)d_ws;

    prep_kernel<<<1, 256, 0, stream>>>(W_emb, b_emb, W_ih, b_ih, b_hh, W_hh,
                                       W_ctrl, W_init, b_init, wsh);
    rollout_kernel<<<BATCH / 128, 512, 0, stream>>>(z, init_state, b_ctrl,
                                                    wsh, out);
}

// Round 11
// 587.305 us; speedup vs baseline: 1.0341x; 1.0341x over previous
//
#include <hip/hip_runtime.h>

typedef _Float16 f16;
typedef _Float16 h8   __attribute__((ext_vector_type(8)));
typedef float    fx16 __attribute__((ext_vector_type(16)));
typedef float    fl2  __attribute__((ext_vector_type(2)));
typedef unsigned int u32x4 __attribute__((ext_vector_type(4)));

#define BATCH   262144
#define SEQ_LEN 30
#define DT      0.03f
#define N2LOG2E (-2.8853900817779268f)

__device__ __forceinline__ float rcpf(float x) { return __builtin_amdgcn_rcpf(x); }
__device__ __forceinline__ float ex2(float x)  { return __builtin_amdgcn_exp2f(x); }
__device__ __forceinline__ float hsum8(h8 v) {
    _Float16 a0 = (_Float16)(v[0] + v[4]);
    _Float16 a1 = (_Float16)(v[1] + v[5]);
    _Float16 a2 = (_Float16)(v[2] + v[6]);
    _Float16 a3 = (_Float16)(v[3] + v[7]);
    return ((float)(_Float16)(a0 + a2)) + ((float)(_Float16)(a1 + a3));
}

// wsh image (f16 units):
//  [0, 20480)     WMAIN frag ((G*4+g)*5+kk) x 64 lanes x 8:
//                 n = g*64 + G*32 + (l&31), k = kk*16 + (l>>5)*8 + e
//                 k<64: W_hh[n][k]*sc; 64-67: Weff[n][k-64]*sc; 68: beff[n]*sc; else 0
//                 sc = -log2(e) for gates i,f,o; -2*log2(e) for gate g
//  [20480, 27648) WINIT frag (G*7+kk2) x 64 x 8 (unscaled)
//  [27648, 27776) WCTRL
__global__ void prep_kernel(const float* __restrict__ W_emb,
                            const float* __restrict__ b_emb,
                            const float* __restrict__ W_ih,
                            const float* __restrict__ b_ih,
                            const float* __restrict__ b_hh,
                            const float* __restrict__ W_hh,
                            const float* __restrict__ W_ctrl,
                            const float* __restrict__ W_init,
                            const float* __restrict__ b_init,
                            f16* __restrict__ wsh) {
    __shared__ float weff_s[256][4];
    __shared__ float beff_s[256];
    {
        int r = threadIdx.x;
        float a0 = 0.f, a1 = 0.f, a2 = 0.f, a3 = 0.f;
        float bb = b_ih[r] + b_hh[r];
        for (int k = 0; k < 64; ++k) {
            float w = W_ih[r * 64 + k];
            a0 = fmaf(w, W_emb[k * 4 + 0], a0);
            a1 = fmaf(w, W_emb[k * 4 + 1], a1);
            a2 = fmaf(w, W_emb[k * 4 + 2], a2);
            a3 = fmaf(w, W_emb[k * 4 + 3], a3);
            bb = fmaf(w, b_emb[k], bb);
        }
        weff_s[r][0] = a0; weff_s[r][1] = a1;
        weff_s[r][2] = a2; weff_s[r][3] = a3;
        beff_s[r] = bb;
    }
    __syncthreads();
    for (int idx = threadIdx.x; idx < 20480; idx += 256) {
        int frag = idx >> 9, rem = idx & 511;
        int l = rem >> 3, e = rem & 7;
        int G  = frag / 20;
        int g  = (frag / 5) & 3;
        int kk = frag % 5;
        int n = g * 64 + G * 32 + (l & 31);
        int k = kk * 16 + (l >> 5) * 8 + e;
        float sc = (g == 2) ? -2.8853900817779268f : -1.4426950408889634f;
        float v;
        if      (k < 64)  v = W_hh[n * 64 + k];
        else if (k < 68)  v = weff_s[n][k - 64];
        else if (k == 68) v = beff_s[n];
        else              v = 0.0f;
        wsh[idx] = (f16)(v * sc);
    }
    for (int idx = threadIdx.x; idx < 7168; idx += 256) {
        int fr = idx >> 9, rem = idx & 511;
        int l = rem >> 3, e = rem & 7;
        int G = fr / 7, kk2 = fr % 7;
        int n = G * 32 + (l & 31);
        int k = kk2 * 16 + (l >> 5) * 8 + e;
        float v = (k < 100) ? W_init[n * 100 + k]
                            : ((k == 100) ? b_init[n] : 0.0f);
        wsh[20480 + idx] = (f16)v;
    }
    if (threadIdx.x < 128) wsh[27648 + threadIdx.x] = (f16)W_ctrl[threadIdx.x];
}

__launch_bounds__(512, 4)
__global__ void rollout_kernel(const float* __restrict__ z,
                               const float* __restrict__ init_state,
                               const float* __restrict__ b_ctrl,
                               const f16* __restrict__ wsh,
                               float* __restrict__ out) {
    __shared__ __align__(16) f16 wmain[20480];       // 40 KB
    __shared__ __align__(16) f16 htile[2][4][2048];  // ping-pong, 32 KB
    __shared__ __align__(16) f16 wctrl[128];

    const int tid  = threadIdx.x;
    const int lane = tid & 63;
    const int wv   = tid >> 6;
    const int team = wv >> 1;
    const int G    = wv & 1;
    const int lrow = lane & 31;
    const int hi   = lane >> 5;
    const int rowbase = blockIdx.x * 128 + team * 32;
    const int lane16  = lane * 16;

    {   // stage weights
        const uint4* src = (const uint4*)wsh;
        uint4* dst = (uint4*)wmain;
        for (int i = tid; i < 2560; i += 512) dst[i] = src[i];
        if (tid < 16) ((uint4*)wctrl)[tid] = ((const uint4*)(wsh + 27648))[tid];
    }

    char* hb       = (char*)&htile[0][team][0];   // +16384 -> buffer 1
    const char* wm = (const char*)wmain;
    const char* wc = (const char*)wctrl;

    // precomputed swizzled LDS byte offsets (loop-invariant)
    const unsigned swz  = (unsigned)((lrow & 7) << 4);
    const unsigned col2 = (unsigned)((G * 32 + lrow) * 2);
    u32x4 rav, rcv, wbv;
    #pragma unroll
    for (int q = 0; q < 4; ++q) {
        rav[q] = (unsigned)(lrow * 128) + ((unsigned)(q * 32 + hi * 16) ^ swz);
        rcv[q] = (unsigned)(lrow * 128) + ((unsigned)(hi * 64 + q * 16) ^ swz);
        wbv[q] = (unsigned)(hi * 512) + (col2 ^ (unsigned)((q + 4 * hi) << 4));
    }

    // ---- init: c0 = h0 = z @ W_init^T + b_init (K=112, bias at k=100) ----
    fx16 cv = {};
    {
        const float* zr   = z + (size_t)(rowbase + lrow) * 100;
        const f16*   wini = wsh + 20480 + G * 7 * 512;
        #pragma unroll
        for (int kk = 0; kk < 6; ++kk) {
            const float4 z0 = *(const float4*)(zr + kk * 16 + hi * 8);
            const float4 z1 = *(const float4*)(zr + kk * 16 + hi * 8 + 4);
            h8 av;
            av[0] = (f16)z0.x; av[1] = (f16)z0.y; av[2] = (f16)z0.z; av[3] = (f16)z0.w;
            av[4] = (f16)z1.x; av[5] = (f16)z1.y; av[6] = (f16)z1.z; av[7] = (f16)z1.w;
            h8 bv = *(const h8*)(wini + kk * 512 + lane * 8);
            cv = __builtin_amdgcn_mfma_f32_32x32x16_f16(av, bv, cv, 0, 0, 0);
        }
        {
            h8 av = {};
            if (hi == 0) {
                const float4 z0 = *(const float4*)(zr + 96);
                av[0] = (f16)z0.x; av[1] = (f16)z0.y;
                av[2] = (f16)z0.z; av[3] = (f16)z0.w;
                av[4] = (f16)1.0f;       // k=100 -> bias
            }
            h8 bv = *(const h8*)(wini + 6 * 512 + lane * 8);
            cv = __builtin_amdgcn_mfma_f32_32x32x16_f16(av, bv, cv, 0, 0, 0);
        }
        #pragma unroll
        for (int r = 0; r < 16; ++r)
            *(f16*)(hb + wbv[r & 3] + ((r >> 2) * 1024 + (r & 3) * 128))
                = (f16)cv[r];
    }

    // plant state: every lane holds row (rowbase + lrow)
    float4 s0 = ((const float4*)init_state)[rowbase + lrow];
    float sx = s0.x, sy = s0.y, sz = s0.z, sw = s0.w;
    const float bc0 = b_ctrl[0], bc1 = b_ctrl[1];
    float4* op = (float4*)out + (size_t)(rowbase + lrow) * SEQ_LEN;

    __syncthreads();   // weights + h0 visible

#define MM(KK, AF)                                                             \
    { h8 bI = *(const h8*)(wm + ((G * 4 + 0) * 5 + (KK)) * 1024 + lane16);     \
      h8 bF = *(const h8*)(wm + ((G * 4 + 1) * 5 + (KK)) * 1024 + lane16);     \
      h8 bG = *(const h8*)(wm + ((G * 4 + 2) * 5 + (KK)) * 1024 + lane16);     \
      h8 bO = *(const h8*)(wm + ((G * 4 + 3) * 5 + (KK)) * 1024 + lane16);     \
      aI  = __builtin_amdgcn_mfma_f32_32x32x16_f16(AF, bI, aI,  0, 0, 0);      \
      aF  = __builtin_amdgcn_mfma_f32_32x32x16_f16(AF, bF, aF,  0, 0, 0);      \
      aGt = __builtin_amdgcn_mfma_f32_32x32x16_f16(AF, bG, aGt, 0, 0, 0);      \
      aO  = __builtin_amdgcn_mfma_f32_32x32x16_f16(AF, bO, aO,  0, 0, 0); }

// POFS/QOFS are literal 0/16384 (ping-pong buffer byte offsets)
#define STEP(POFS, QOFS, T) do {                                               \
    h8 af0 = *(const h8*)(hb + (POFS) + rav[0]);                               \
    h8 af1 = *(const h8*)(hb + (POFS) + rav[1]);                               \
    h8 af2 = *(const h8*)(hb + (POFS) + rav[2]);                               \
    h8 af3 = *(const h8*)(hb + (POFS) + rav[3]);                               \
    h8 af4 = {};                                                               \
    if (hi == 0) {                                                             \
        af4[0] = (f16)sx; af4[1] = (f16)sy;                                    \
        af4[2] = (f16)sz; af4[3] = (f16)sw;                                    \
        af4[4] = (f16)1.0f;                                                    \
    }                                                                          \
    fx16 aI = {}, aF = {}, aGt = {}, aO = {};                                  \
    MM(0, af0) MM(1, af1) MM(2, af2) MM(3, af3) MM(4, af4)                     \
    _Pragma("unroll")                                                          \
    for (int r2 = 0; r2 < 8; ++r2) {                                           \
        const int r = 2 * r2;                                                  \
        fl2 eI = { ex2(aI[r]),  ex2(aI[r + 1])  };                             \
        fl2 eF = { ex2(aF[r]),  ex2(aF[r + 1])  };                             \
        fl2 eG = { ex2(aGt[r]), ex2(aGt[r + 1]) };                             \
        fl2 eO = { ex2(aO[r]),  ex2(aO[r + 1])  };                             \
        fl2 pF  = 1.0f + eF;                                                   \
        fl2 P   = (1.0f + eI) * (1.0f + eG);                                   \
        fl2 cvp = { cv[r], cv[r + 1] };                                        \
        fl2 num = __builtin_elementwise_fma(cvp, P, (1.0f - eG) * pF);         \
        fl2 dP  = pF * P;                                                      \
        fl2 rdP = { rcpf(dP[0]), rcpf(dP[1]) };                                \
        fl2 cc  = num * rdP;                                                   \
        cv[r] = cc[0]; cv[r + 1] = cc[1];                                      \
        fl2 ccn = cc * N2LOG2E;                                                \
        fl2 eC  = { ex2(ccn[0]), ex2(ccn[1]) };                                \
        fl2 den = (1.0f + eO) * (1.0f + eC);                                   \
        fl2 rdn = { rcpf(den[0]), rcpf(den[1]) };                              \
        fl2 hn  = (1.0f - eC) * rdn;                                           \
        *(f16*)(hb + (QOFS) + wbv[r & 3] + ((r >> 2) * 1024 + (r & 3) * 128))  \
            = (f16)hn[0];                                                      \
        *(f16*)(hb + (QOFS) + wbv[(r + 1) & 3]                                 \
                + (((r + 1) >> 2) * 1024 + ((r + 1) & 3) * 128))               \
            = (f16)hn[1];                                                      \
    }                                                                          \
    __syncthreads();                                                           \
    h8 pv = {}, qv = {};                                                       \
    _Pragma("unroll")                                                          \
    for (int jj = 0; jj < 4; ++jj) {                                           \
        h8 hv = *(const h8*)(hb + (QOFS) + rcv[jj]);                           \
        h8 w0 = *(const h8*)(wc + hi * 64 + jj * 16);                          \
        h8 w1 = *(const h8*)(wc + 128 + hi * 64 + jj * 16);                    \
        pv = __builtin_elementwise_fma(hv, w0, pv);                            \
        qv = __builtin_elementwise_fma(hv, w1, qv);                            \
    }                                                                          \
    float pp = hsum8(pv), qq = hsum8(qv);                                      \
    float ped = bc0 + pp + __shfl_xor(pp, 32);                                 \
    float str = bc1 + qq + __shfl_xor(qq, 32);                                 \
    float beta = fminf(0.5f, fmaxf(-0.5f, str));                               \
    float v1   = fminf(10.0f, fmaxf(0.0f, fmaf(ped, DT, sw)));                 \
    float cpsi = __cosf(sz);                                                   \
    float spsi = __sinf(sz);                                                   \
    float b2   = beta * beta;                                                  \
    float tb   = beta * fmaf(b2, fmaf(b2, fmaf(b2, 0.05396825397f,             \
                         0.13333333333f), 0.33333333333f), 1.0f);              \
    float psid = fminf(1.57f, fmaxf(-1.57f, sw * tb * 0.4f));                  \
    sx = fmaf(v1 * cpsi, DT, sx);                                              \
    sy = fmaf(v1 * spsi, DT, sy);                                              \
    sz = fmaf(psid, DT, sz);                                                   \
    sw = v1;                                                                   \
    if (G == 0 && lane < 32) op[(T)] = make_float4(sx, sy, sz, sw);            \
} while (0)

    #pragma unroll 1
    for (int t2 = 0; t2 < SEQ_LEN; t2 += 2) {
        STEP(0, 16384, t2);
        STEP(16384, 0, t2 + 1);
    }
#undef STEP
#undef MM
}

extern "C" void kernel_launch(void* const* d_in, const int* in_sizes, int n_in,
                              void* d_out, int out_size, void* d_ws, size_t ws_size,
                              hipStream_t stream) {
    const float* z          = (const float*)d_in[0];
    const float* init_state = (const float*)d_in[1];
    const float* W_emb      = (const float*)d_in[2];
    const float* b_emb      = (const float*)d_in[3];
    const float* W_ih       = (const float*)d_in[4];
    const float* W_hh       = (const float*)d_in[5];
    const float* b_ih       = (const float*)d_in[6];
    const float* b_hh       = (const float*)d_in[7];
    const float* W_ctrl     = (const float*)d_in[8];
    const float* b_ctrl     = (const float*)d_in[9];
    const float* W_init     = (const float*)d_in[10];
    const float* b_init     = (const float*)d_in[11];
    float* out = (float*)d_out;
    f16*   wsh = (f16*)d_ws;

    prep_kernel<<<1, 256, 0, stream>>>(W_emb, b_emb, W_ih, b_ih, b_hh, W_hh,
                                       W_ctrl, W_init, b_init, wsh);
    rollout_kernel<<<BATCH / 128, 512, 0, stream>>>(z, init_state, b_ctrl,
                                                    wsh, out);
}